// Round 2
// baseline (662.403 us; speedup 1.0000x reference)
//
#include <hip/hip_runtime.h>
#include <hip/hip_bf16.h>
#include <math.h>

// N=1, D=17, Dp=16, S=128, H=2048, NH=16, HD=128, K=16, Sk=128

typedef __attribute__((ext_vector_type(8))) short bf16x8;
typedef __attribute__((ext_vector_type(4))) short bf16x4;
typedef __attribute__((ext_vector_type(4))) float f32x4;

__device__ __forceinline__ unsigned short f2bf(float f) {
    union { float f; unsigned u; } c; c.f = f;
    unsigned u = c.u + 0x7FFF + ((c.u >> 16) & 1);   // RNE
    return (unsigned short)(u >> 16);
}

__device__ __forceinline__ void gload16(const void* g, void* l) {
    __builtin_amdgcn_global_load_lds((const __attribute__((address_space(1))) void*)g,
                                     (__attribute__((address_space(3))) void*)l, 16, 0, 0);
}

// ---------------- RMSNorm (rows 128..2175 of hidden_states) -> bf16 xn (2048x2048)
__global__ __launch_bounds__(256) void rms_kernel(const float* __restrict__ hs,
                                                  const float* __restrict__ rw,
                                                  unsigned short* __restrict__ xn) {
    int row = blockIdx.x;
    const float* x = hs + (size_t)(row + 128) * 2048;
    int tid = threadIdx.x;
    float4 a = ((const float4*)x)[tid * 2];
    float4 b = ((const float4*)x)[tid * 2 + 1];
    float ss = a.x*a.x + a.y*a.y + a.z*a.z + a.w*a.w
             + b.x*b.x + b.y*b.y + b.z*b.z + b.w*b.w;
#pragma unroll
    for (int m = 1; m < 64; m <<= 1) ss += __shfl_xor(ss, m);
    __shared__ float part[4];
    if ((tid & 63) == 0) part[tid >> 6] = ss;
    __syncthreads();
    float tot = part[0] + part[1] + part[2] + part[3];
    float rstd = rsqrtf(tot * (1.0f / 2048.0f) + 1e-6f);
    float4 wa = ((const float4*)rw)[tid * 2];
    float4 wb = ((const float4*)rw)[tid * 2 + 1];
    bf16x8 o;
    o[0] = (short)f2bf(a.x * rstd * wa.x);
    o[1] = (short)f2bf(a.y * rstd * wa.y);
    o[2] = (short)f2bf(a.z * rstd * wa.z);
    o[3] = (short)f2bf(a.w * rstd * wa.w);
    o[4] = (short)f2bf(b.x * rstd * wb.x);
    o[5] = (short)f2bf(b.y * rstd * wb.y);
    o[6] = (short)f2bf(b.z * rstd * wb.z);
    o[7] = (short)f2bf(b.w * rstd * wb.w);
    *reinterpret_cast<bf16x8*>(&xn[(size_t)row * 2048 + tid * 8]) = o;
}

// ---------------- fp32 -> bf16 elementwise cast (4M elems)
__global__ __launch_bounds__(256) void cast_kernel(const float* __restrict__ in,
                                                   unsigned short* __restrict__ out) {
    size_t i = ((size_t)blockIdx.x * 256 + threadIdx.x) * 8;
    float4 a = *reinterpret_cast<const float4*>(in + i);
    float4 b = *reinterpret_cast<const float4*>(in + i + 4);
    bf16x8 o;
    o[0] = (short)f2bf(a.x); o[1] = (short)f2bf(a.y);
    o[2] = (short)f2bf(a.z); o[3] = (short)f2bf(a.w);
    o[4] = (short)f2bf(b.x); o[5] = (short)f2bf(b.y);
    o[6] = (short)f2bf(b.z); o[7] = (short)f2bf(b.w);
    *reinterpret_cast<bf16x8*>(out + i) = o;
}

// ---------------- split-K GEMM: C(2048x2048) += A(2048x2048) * B(2048x2048)^T
// bf16 in, fp32 atomic out. 128x128 tile, BK=64, global_load_lds staging,
// grid = 16mt x 16nt x 2ksplit = 512 blocks (2 blocks/CU), 4 waves.
__global__ __launch_bounds__(256, 2) void gemm_ks(const unsigned short* __restrict__ A,
                                                  const unsigned short* __restrict__ B,
                                                  float* __restrict__ C) {
    __shared__ short As[128 * 64];
    __shared__ short Bs[128 * 64];
    int bid = blockIdx.x;
    int ksl = bid & 1;
    int bn = ((bid >> 1) & 15) * 128;
    int bm = (bid >> 5) * 128;
    int tid = threadIdx.x;
    int lane = tid & 63, wid = tid >> 6;
    int wm = (wid >> 1) * 64, wn = (wid & 1) * 64;
    int r16 = lane & 15, g = lane >> 4;
    f32x4 acc[4][4] = {};
    int k0 = ksl * 1024;

    for (int kt = k0; kt < k0 + 1024; kt += 64) {
#pragma unroll
        for (int p = 0; p < 4; ++p) {
            int idx = p * 256 + tid;
            int r = idx >> 3, c = (idx & 7) * 8;
            gload16(&A[(size_t)(bm + r) * 2048 + kt + c], (void*)&As[idx * 8]);
            gload16(&B[(size_t)(bn + r) * 2048 + kt + c], (void*)&Bs[idx * 8]);
        }
        __syncthreads();
#pragma unroll
        for (int ks = 0; ks < 2; ++ks) {
            bf16x8 af[4], bfr[4];
#pragma unroll
            for (int i = 0; i < 4; ++i) {
                af[i]  = *reinterpret_cast<const bf16x8*>(&As[(wm + i * 16 + r16) * 64 + ks * 32 + g * 8]);
                bfr[i] = *reinterpret_cast<const bf16x8*>(&Bs[(wn + i * 16 + r16) * 64 + ks * 32 + g * 8]);
            }
#pragma unroll
            for (int i = 0; i < 4; ++i)
#pragma unroll
                for (int j = 0; j < 4; ++j)
                    acc[i][j] = __builtin_amdgcn_mfma_f32_16x16x32_bf16(af[i], bfr[j], acc[i][j], 0, 0, 0);
        }
        __syncthreads();
    }
#pragma unroll
    for (int i = 0; i < 4; ++i) {
        int row0 = bm + wm + i * 16 + g * 4;
#pragma unroll
        for (int j = 0; j < 4; ++j) {
            int col = bn + wn + j * 16 + r16;
#pragma unroll
            for (int rr = 0; rr < 4; ++rr)
                atomicAdd(&C[(size_t)(row0 + rr) * 2048 + col], acc[i][j][rr]);
        }
    }
}

// ---------------- Attention, register-double-buffered K/V pipeline.
// grid 256 = (dp, h), 512 threads (8 waves). Q fp32 -> bf16 frags once.
__global__ __launch_bounds__(512, 2) void attn_kernel(const float* __restrict__ qf,
                                                      const float* __restrict__ ck,
                                                      const float* __restrict__ cv,
                                                      const float* __restrict__ wts,
                                                      unsigned short* __restrict__ o2d) {
    int dp = blockIdx.x >> 4;
    int h  = blockIdx.x & 15;
    int tid = threadIdx.x;
    int lane = tid & 63, w = tid >> 6;
    int r16 = lane & 15, g = lane >> 4;

    __shared__ short kbuf[128 * 136];   // K[t][hd]
    __shared__ short vtbuf[128 * 136];  // V^T[hd][t]
    __shared__ short pbuf[128 * 136];   // P[s][t] (per-wave private rows)

    // Q fragments (fp32 -> bf16)
    bf16x8 qfr[4];
    {
        const float* qrow = qf + (size_t)(dp * 128 + w * 16 + r16) * 2048 + h * 128 + g * 8;
#pragma unroll
        for (int ks = 0; ks < 4; ++ks) {
            float4 a = *reinterpret_cast<const float4*>(qrow + ks * 32);
            float4 b = *reinterpret_cast<const float4*>(qrow + ks * 32 + 4);
            bf16x8 q8;
            q8[0] = (short)f2bf(a.x); q8[1] = (short)f2bf(a.y);
            q8[2] = (short)f2bf(a.z); q8[3] = (short)f2bf(a.w);
            q8[4] = (short)f2bf(b.x); q8[5] = (short)f2bf(b.y);
            q8[6] = (short)f2bf(b.z); q8[7] = (short)f2bf(b.w);
            qfr[ks] = q8;
        }
    }

    // staging geometry
    int kt_row = tid >> 5;          // 0..15
    int khd0   = (tid & 31) * 4;    // 0..124
    int vhd    = tid & 127;         // 0..127
    int vtg    = tid >> 7;          // 0..3

    float4 kpre[8];
    float  vpre[32];
    // PREFETCH chunk 0
    {
        size_t cb = (size_t)(dp * 16) * 128 * 2048 + h * 128;
#pragma unroll
        for (int p = 0; p < 8; ++p)
            kpre[p] = *reinterpret_cast<const float4*>(&ck[cb + (size_t)(p * 16 + kt_row) * 2048 + khd0]);
#pragma unroll
        for (int p = 0; p < 4; ++p)
#pragma unroll
            for (int j = 0; j < 8; ++j)
                vpre[p * 8 + j] = cv[cb + (size_t)(p * 32 + vtg * 8 + j) * 2048 + vhd];
    }

    f32x4 oacc[8] = {};
    const float sc = 0.088388347648318447f * 1.44269504088896f;  // 1/sqrt(128)*log2(e)

    for (int k = 0; k < 16; ++k) {
        // CONVERT + WRITE chunk k from prefetch registers into LDS
#pragma unroll
        for (int p = 0; p < 8; ++p) {
            int t = p * 16 + kt_row;
            bf16x4 s4;
            s4[0] = (short)f2bf(kpre[p].x); s4[1] = (short)f2bf(kpre[p].y);
            s4[2] = (short)f2bf(kpre[p].z); s4[3] = (short)f2bf(kpre[p].w);
            *reinterpret_cast<bf16x4*>(&kbuf[t * 136 + khd0]) = s4;
        }
#pragma unroll
        for (int p = 0; p < 4; ++p) {
            bf16x8 s8;
#pragma unroll
            for (int j = 0; j < 8; ++j)
                s8[j] = (short)f2bf(vpre[p * 8 + j]);
            *reinterpret_cast<bf16x8*>(&vtbuf[vhd * 136 + p * 32 + vtg * 8]) = s8;
        }
        __syncthreads();

        // PREFETCH chunk k+1 (overlaps with compute below)
        if (k < 15) {
            size_t cb = (size_t)(dp * 16 + k + 1) * 128 * 2048 + h * 128;
#pragma unroll
            for (int p = 0; p < 8; ++p)
                kpre[p] = *reinterpret_cast<const float4*>(&ck[cb + (size_t)(p * 16 + kt_row) * 2048 + khd0]);
#pragma unroll
            for (int p = 0; p < 4; ++p)
#pragma unroll
                for (int j = 0; j < 8; ++j)
                    vpre[p * 8 + j] = cv[cb + (size_t)(p * 32 + vtg * 8 + j) * 2048 + vhd];
        }

        // QK^T
        f32x4 sacc[8] = {};
#pragma unroll
        for (int ks = 0; ks < 4; ++ks) {
#pragma unroll
            for (int nb = 0; nb < 8; ++nb) {
                bf16x8 kf = *reinterpret_cast<const bf16x8*>(&kbuf[(nb * 16 + r16) * 136 + ks * 32 + g * 8]);
                sacc[nb] = __builtin_amdgcn_mfma_f32_16x16x32_bf16(qfr[ks], kf, sacc[nb], 0, 0, 0);
            }
        }

        // register softmax over t, fold chunk weight
        float wdk = wts[dp * 16 + k];
        float fac[4];
#pragma unroll
        for (int r = 0; r < 4; ++r) {
            float m = sacc[0][r];
#pragma unroll
            for (int nb = 1; nb < 8; ++nb) m = fmaxf(m, sacc[nb][r]);
            m = fmaxf(m, __shfl_xor(m, 1));
            m = fmaxf(m, __shfl_xor(m, 2));
            m = fmaxf(m, __shfl_xor(m, 4));
            m = fmaxf(m, __shfl_xor(m, 8));
            float s = 0.f;
#pragma unroll
            for (int nb = 0; nb < 8; ++nb) {
                float p = exp2f((sacc[nb][r] - m) * sc);
                sacc[nb][r] = p;
                s += p;
            }
            s += __shfl_xor(s, 1);
            s += __shfl_xor(s, 2);
            s += __shfl_xor(s, 4);
            s += __shfl_xor(s, 8);
            fac[r] = wdk / s;
        }
        // P -> LDS (wave-private rows)
#pragma unroll
        for (int r = 0; r < 4; ++r)
#pragma unroll
            for (int nb = 0; nb < 8; ++nb)
                pbuf[(w * 16 + g * 4 + r) * 136 + nb * 16 + r16] = (short)f2bf(sacc[nb][r] * fac[r]);

        // PV
#pragma unroll
        for (int ks = 0; ks < 4; ++ks) {
            bf16x8 pf = *reinterpret_cast<const bf16x8*>(&pbuf[(w * 16 + r16) * 136 + ks * 32 + g * 8]);
#pragma unroll
            for (int nb = 0; nb < 8; ++nb) {
                bf16x8 vf = *reinterpret_cast<const bf16x8*>(&vtbuf[(nb * 16 + r16) * 136 + ks * 32 + g * 8]);
                oacc[nb] = __builtin_amdgcn_mfma_f32_16x16x32_bf16(pf, vf, oacc[nb], 0, 0, 0);
            }
        }
        __syncthreads();   // all waves done reading kbuf/vtbuf
    }

    // epilogue: o2d[dp*128 + s][h*128 + hd] bf16
#pragma unroll
    for (int nb = 0; nb < 8; ++nb) {
#pragma unroll
        for (int rr = 0; rr < 4; ++rr) {
            int row = dp * 128 + w * 16 + g * 4 + rr;
            int col = h * 128 + nb * 16 + r16;
            o2d[(size_t)row * 2048 + col] = f2bf(oacc[nb][rr]);
        }
    }
}

extern "C" void kernel_launch(void* const* d_in, const int* in_sizes, int n_in,
                              void* d_out, int out_size, void* d_ws, size_t ws_size,
                              hipStream_t stream) {
    const float* hs  = (const float*)d_in[0];
    const float* ck  = (const float*)d_in[1];
    const float* cv  = (const float*)d_in[2];
    const float* wts = (const float*)d_in[3];
    const float* rw  = (const float*)d_in[4];
    const float* Wq  = (const float*)d_in[5];
    const float* Wo  = (const float*)d_in[6];
    float* out = (float*)d_out;

    char* ws = (char*)d_ws;
    unsigned short* xn  = (unsigned short*)(ws);                 // 8MB (reused as o2d)
    unsigned short* wqb = (unsigned short*)(ws + (8u  << 20));   // 8MB (reused as Wo bf16)
    float*          qf  = (float*)        (ws + (16u << 20));    // 16MB fp32 Q
    unsigned short* o2d = xn;
    unsigned short* wob = wqb;

    // zero atomic-accumulation targets (ws/out are poisoned before every call)
    hipMemsetAsync(out, 0, (size_t)17 * 128 * 2048 * 4, stream);
    hipMemsetAsync(qf, 0, (size_t)2048 * 2048 * 4, stream);

    cast_kernel<<<2048, 256, 0, stream>>>(Wq, wqb);
    rms_kernel<<<2048, 256, 0, stream>>>(hs, rw, xn);
    gemm_ks<<<512, 256, 0, stream>>>(xn, wqb, qf);                       // Q = xn * Wq^T (fp32)
    attn_kernel<<<256, 512, 0, stream>>>(qf, ck, cv, wts, o2d);
    cast_kernel<<<2048, 256, 0, stream>>>(Wo, wob);
    gemm_ks<<<512, 256, 0, stream>>>(o2d, wob, out + (size_t)128 * 2048); // O = o2d * Wo^T
}